// Round 10
// baseline (307.708 us; speedup 1.0000x reference)
//
#include <hip/hip_runtime.h>

// R10: R9 LDS-staged pipeline + TWO q-tiles (128 rows) per item (each LDS
// K/V fragment read feeds both q-sets' MFMAs -> halves LDS bytes/flop and
// halves staging+barrier cost per unit work) + 8 per-XCD subqueues (same-(b,h)
// items pop consecutively on one XCD -> L2 reuse). Uniform code: causal mask
// zeroes A beyond its limit; padded B rows get inv=0.

#define BB 4
#define QQ 1024
#define SS 2048
#define HH 32
#define DD 128
#define QT 64
#define KT 32
#define NTILES 64
#define TILE_ELEMS 4096
#define NPERQ 128     // items per XCD residue queue (16 bh x 8 pairs)

typedef __attribute__((ext_vector_type(8))) short short8;
typedef __attribute__((ext_vector_type(4))) float f32x4;
typedef __attribute__((ext_vector_type(4))) unsigned int u32x4;
typedef __attribute__((ext_vector_type(8))) unsigned short u16x8;

__device__ __forceinline__ unsigned short f2bf(float f) {
    unsigned int u = __builtin_bit_cast(unsigned int, f);
    u += 0x7FFFu + ((u >> 16) & 1u);
    return (unsigned short)(u >> 16);
}
__device__ __forceinline__ unsigned int pk2(float a, float b) {
    return (unsigned int)f2bf(a) | ((unsigned int)f2bf(b) << 16);
}

// ---------------- prep: f32 cache/new -> bf16 lane-linear fragment ws ----------
__global__ __launch_bounds__(256)
void prep(const float* __restrict__ ks, const float* __restrict__ vs,
          const float* __restrict__ kc, const float* __restrict__ vc,
          const int* __restrict__ qlens, const int* __restrict__ clens,
          unsigned short* __restrict__ Kws, unsigned short* __restrict__ Vws)
{
    const int tile = blockIdx.x, h = blockIdx.y, b = blockIdx.z;
    const int qlen = qlens[b], clen = clens[b];
    if (tile * KT >= clen + qlen) return;
    const int tid = threadIdx.x;
    unsigned short* kout = Kws + (((size_t)b * HH + h) * NTILES + tile) * TILE_ELEMS;
    unsigned short* vout = Vws + (((size_t)b * HH + h) * NTILES + tile) * TILE_ELEMS;

    #pragma unroll
    for (int half = 0; half < 2; ++half) {
        const int key15 = tid & 15, gk = (tid >> 4) & 3, c = tid >> 6;
        int key = tile * KT + half * 16 + key15;
        const float* src;
        if (key < clen) {
            src = kc + (((size_t)b * SS + key) * HH + h) * DD;
        } else {
            int i2 = key - clen; if (i2 > QQ - 1) i2 = QQ - 1;
            src = ks + (((size_t)b * QQ + i2) * HH + h) * DD;
        }
        const int d0 = c * 32 + gk * 8;
        f32x4 a0 = *(const f32x4*)&src[d0];
        f32x4 a1 = *(const f32x4*)&src[d0 + 4];
        u16x8 w;
        w[0] = f2bf(a0[0]); w[1] = f2bf(a0[1]); w[2] = f2bf(a0[2]); w[3] = f2bf(a0[3]);
        w[4] = f2bf(a1[0]); w[5] = f2bf(a1[1]); w[6] = f2bf(a1[2]); w[7] = f2bf(a1[3]);
        *(u16x8*)&kout[half * 2048 + tid * 8] = w;
    }
    #pragma unroll
    for (int it = 0; it < 2; ++it) {
        const int w_ = it * 256 + tid;
        const int lcv = w_ & 15, gv = (w_ >> 4) & 3, n = w_ >> 6;
        const int d = n * 16 + lcv;
        u16x8 w;
        #pragma unroll
        for (int e = 0; e < 8; ++e) {
            int key = tile * KT + gv * 8 + e;
            const float* src;
            if (key < clen) {
                src = vc + (((size_t)b * SS + key) * HH + h) * DD;
            } else {
                int i2 = key - clen; if (i2 > QQ - 1) i2 = QQ - 1;
                src = vs + (((size_t)b * QQ + i2) * HH + h) * DD;
            }
            w[e] = f2bf(src[d]);
        }
        *(u16x8*)&vout[w_ * 8] = w;
    }
}

// ---------------- hot: per-XCD queues + LDS tiles + 2 q-tiles/item ----------
__global__ __launch_bounds__(256)
void segattn_persist(const float* __restrict__ qs, const int* __restrict__ qlens,
                     const int* __restrict__ clens,
                     const unsigned short* __restrict__ Kws,
                     const unsigned short* __restrict__ Vws,
                     float* __restrict__ out, int* __restrict__ counter)
{
    __shared__ int s_item;
    alignas(16) __shared__ unsigned short KVl[2][8192];  // K [0,4096) V [4096,8192) hw

    const int tid = threadIdx.x, wave = tid >> 6, lane = tid & 63;
    const int g = lane >> 4, lc = lane & 15;
    const float psc = 0.08838834764831845f * 1.4426950408889634f;
    const int srcE = ((g & 1) << 1);
    const int addrE = ((srcE << 4) + lc) << 2;
    const int addrO = addrE + 64;
    const bool useB = (g >= 2);
    const int whw = wave * 1024 + lane * 8;
    const int cres = blockIdx.x & 7;                 // XCD residue (round-robin heuristic)
    int* myctr = counter + cres;

    for (;;) {
        if (tid == 0) s_item = atomicAdd(myctr, 1);
        __syncthreads();
        const int pop = s_item;
        __syncthreads();
        if (pop >= NPERQ) break;

        const int bh = cres + (pop & ~7);            // bh-major: 8 pairs consecutive
        const int jt = 7 - (pop & 7);                // heavy pair first
        const int b = bh & 3, h = bh >> 2;
        const int qlen = qlens[b], clen = clens[b];
        const int q0 = jt * 128;                     // A: q0..q0+63, B: q0+64..q0+127

        if (q0 >= qlen) {                            // both tiles padded -> zeros
            f32x4 z = {0.f, 0.f, 0.f, 0.f};
            #pragma unroll
            for (int i2 = 0; i2 < 16; ++i2) {
                int f = tid + i2 * 256;
                int r = f >> 5, d4 = f & 31;
                *(f32x4*)&out[(((size_t)b * QQ + q0 + r) * HH + h) * DD + d4 * 4] = z;
            }
            continue;
        }

        const int qA = q0 + wave * 16 + lc, qB = qA + 64;
        const float* qpA = qs + (((size_t)b * QQ + qA) * HH + h) * DD;
        const float* qpB = qs + (((size_t)b * QQ + qB) * HH + h) * DD;
        short8 qfA[4], qfB[4];
        #pragma unroll
        for (int c = 0; c < 4; ++c) {
            f32x4 a0 = *(const f32x4*)&qpA[c * 32 + g * 8];
            f32x4 a1 = *(const f32x4*)&qpA[c * 32 + g * 8 + 4];
            f32x4 b0 = *(const f32x4*)&qpB[c * 32 + g * 8];
            f32x4 b1 = *(const f32x4*)&qpB[c * 32 + g * 8 + 4];
            short8 ta, tb;
            ta[0] = (short)f2bf(a0[0] * psc); ta[1] = (short)f2bf(a0[1] * psc);
            ta[2] = (short)f2bf(a0[2] * psc); ta[3] = (short)f2bf(a0[3] * psc);
            ta[4] = (short)f2bf(a1[0] * psc); ta[5] = (short)f2bf(a1[1] * psc);
            ta[6] = (short)f2bf(a1[2] * psc); ta[7] = (short)f2bf(a1[3] * psc);
            tb[0] = (short)f2bf(b0[0] * psc); tb[1] = (short)f2bf(b0[1] * psc);
            tb[2] = (short)f2bf(b0[2] * psc); tb[3] = (short)f2bf(b0[3] * psc);
            tb[4] = (short)f2bf(b1[0] * psc); tb[5] = (short)f2bf(b1[1] * psc);
            tb[6] = (short)f2bf(b1[2] * psc); tb[7] = (short)f2bf(b1[3] * psc);
            qfA[c] = ta; qfB[c] = tb;
        }

        const int limA = (qA < qlen) ? (clen + qA + 1) : 0;
        const int limB = (qB < qlen) ? (clen + qB + 1) : 0;
        const int wq0A = q0 + (__builtin_amdgcn_readfirstlane(wave) << 4);
        const int wq0B = wq0A + 64;
        const int lim_minA = (wq0A + 15 < qlen) ? (clen + wq0A + 1) : 0;
        const int lim_minB = (wq0B + 15 < qlen) ? (clen + wq0B + 1) : 0;

        float mA = -3e38f, lA = 0.f, mB = -3e38f, lB = 0.f;
        f32x4 oA[8], oB[8];
        #pragma unroll
        for (int n = 0; n < 8; ++n) {
            oA[n] = (f32x4){0.f, 0.f, 0.f, 0.f};
            oB[n] = (f32x4){0.f, 0.f, 0.f, 0.f};
        }

        const int kmax = clen + min(q0 + 128, qlen);
        const int nt = (kmax + KT - 1) / KT;
        const unsigned short* Kb = Kws + ((size_t)(b * HH + h)) * NTILES * TILE_ELEMS;
        const unsigned short* Vb = Vws + ((size_t)(b * HH + h)) * NTILES * TILE_ELEMS;

        // ---- prologue: tile 0 -> buf0
        {
            u32x4 a0 = *(const u32x4*)&Kb[whw];
            u32x4 a1 = *(const u32x4*)&Kb[whw + 512];
            u32x4 a2 = *(const u32x4*)&Vb[whw];
            u32x4 a3 = *(const u32x4*)&Vb[whw + 512];
            *(u32x4*)&KVl[0][whw]              = a0;
            *(u32x4*)&KVl[0][whw + 512]        = a1;
            *(u32x4*)&KVl[0][4096 + whw]       = a2;
            *(u32x4*)&KVl[0][4096 + whw + 512] = a3;
            asm volatile("s_waitcnt lgkmcnt(0)" ::: "memory");
            __builtin_amdgcn_s_barrier();
            __builtin_amdgcn_sched_barrier(0);
        }
        const int t1 = (nt > 1) ? 1 : 0;
        const unsigned short* kt1 = Kb + (size_t)t1 * TILE_ELEMS;
        const unsigned short* vt1 = Vb + (size_t)t1 * TILE_ELEMS;
        u32x4 sk0 = *(const u32x4*)&kt1[whw];
        u32x4 sk1 = *(const u32x4*)&kt1[whw + 512];
        u32x4 sv0 = *(const u32x4*)&vt1[whw];
        u32x4 sv1 = *(const u32x4*)&vt1[whw + 512];

        int cur = 0;
        for (int t = 0; t < nt; ++t) {
            const int nb = cur ^ 1;
            *(u32x4*)&KVl[nb][whw]              = sk0;
            *(u32x4*)&KVl[nb][whw + 512]        = sk1;
            *(u32x4*)&KVl[nb][4096 + whw]       = sv0;
            *(u32x4*)&KVl[nb][4096 + whw + 512] = sv1;
            const int t2c = (t + 2 < nt) ? t + 2 : (nt - 1);
            const unsigned short* kt2 = Kb + (size_t)t2c * TILE_ELEMS;
            const unsigned short* vt2 = Vb + (size_t)t2c * TILE_ELEMS;
            sk0 = *(const u32x4*)&kt2[whw];
            sk1 = *(const u32x4*)&kt2[whw + 512];
            sv0 = *(const u32x4*)&vt2[whw];
            sv1 = *(const u32x4*)&vt2[whw + 512];
            asm volatile("s_waitcnt lgkmcnt(0)" ::: "memory");
            __builtin_amdgcn_s_barrier();
            __builtin_amdgcn_sched_barrier(0);

            // ---- compute tile t for BOTH q-tiles; each k/v LDS read shared
            const unsigned short* Kc = &KVl[cur][0];
            const int pbase = t * KT;
            f32x4 sA0 = {0.f,0.f,0.f,0.f}, sA1 = {0.f,0.f,0.f,0.f};
            f32x4 sB0 = {0.f,0.f,0.f,0.f}, sB1 = {0.f,0.f,0.f,0.f};
            #pragma unroll
            for (int c = 0; c < 4; ++c) {
                short8 k0 = *(const short8*)&Kc[c * 512 + lane * 8];
                short8 k1 = *(const short8*)&Kc[2048 + c * 512 + lane * 8];
                sA0 = __builtin_amdgcn_mfma_f32_16x16x32_bf16(k0, qfA[c], sA0, 0, 0, 0);
                sA1 = __builtin_amdgcn_mfma_f32_16x16x32_bf16(k1, qfA[c], sA1, 0, 0, 0);
                sB0 = __builtin_amdgcn_mfma_f32_16x16x32_bf16(k0, qfB[c], sB0, 0, 0, 0);
                sB1 = __builtin_amdgcn_mfma_f32_16x16x32_bf16(k1, qfB[c], sB1, 0, 0, 0);
            }
            const int kg0 = pbase + g * 4, kg1 = kg0 + 16;
            if (pbase + KT > lim_minA) {
                #pragma unroll
                for (int r = 0; r < 4; ++r) {
                    if (kg0 + r >= limA) sA0[r] = -3e38f;
                    if (kg1 + r >= limA) sA1[r] = -3e38f;
                }
            }
            if (pbase + KT > lim_minB) {
                #pragma unroll
                for (int r = 0; r < 4; ++r) {
                    if (kg0 + r >= limB) sB0[r] = -3e38f;
                    if (kg1 + r >= limB) sB1[r] = -3e38f;
                }
            }

            // ---- softmax A
            float pmA = fmaxf(fmaxf(fmaxf(sA0[0], sA0[1]), fmaxf(sA0[2], sA0[3])),
                              fmaxf(fmaxf(sA1[0], sA1[1]), fmaxf(sA1[2], sA1[3])));
            if (__any(pmA > mA + 8.0f)) {
                pmA = fmaxf(pmA, __shfl_xor(pmA, 16));
                pmA = fmaxf(pmA, __shfl_xor(pmA, 32));
                const float mn = fmaxf(mA, pmA);
                const float alpha = __builtin_amdgcn_exp2f(mA - mn);
                mA = mn; lA *= alpha;
                #pragma unroll
                for (int n = 0; n < 8; ++n) {
                    oA[n][0] *= alpha; oA[n][1] *= alpha;
                    oA[n][2] *= alpha; oA[n][3] *= alpha;
                }
            }
            float pA[8];
            #pragma unroll
            for (int r = 0; r < 4; ++r) {
                pA[r]     = __builtin_amdgcn_exp2f(sA0[r] - mA);
                pA[4 + r] = __builtin_amdgcn_exp2f(sA1[r] - mA);
            }
            lA += ((pA[0]+pA[1])+(pA[2]+pA[3])) + ((pA[4]+pA[5])+(pA[6]+pA[7]));

            // ---- softmax B
            float pmB = fmaxf(fmaxf(fmaxf(sB0[0], sB0[1]), fmaxf(sB0[2], sB0[3])),
                              fmaxf(fmaxf(sB1[0], sB1[1]), fmaxf(sB1[2], sB1[3])));
            if (__any(pmB > mB + 8.0f)) {
                pmB = fmaxf(pmB, __shfl_xor(pmB, 16));
                pmB = fmaxf(pmB, __shfl_xor(pmB, 32));
                const float mn = fmaxf(mB, pmB);
                const float alpha = __builtin_amdgcn_exp2f(mB - mn);
                mB = mn; lB *= alpha;
                #pragma unroll
                for (int n = 0; n < 8; ++n) {
                    oB[n][0] *= alpha; oB[n][1] *= alpha;
                    oB[n][2] *= alpha; oB[n][3] *= alpha;
                }
            }
            float pB[8];
            #pragma unroll
            for (int r = 0; r < 4; ++r) {
                pB[r]     = __builtin_amdgcn_exp2f(sB0[r] - mB);
                pB[4 + r] = __builtin_amdgcn_exp2f(sB1[r] - mB);
            }
            lB += ((pB[0]+pB[1])+(pB[2]+pB[3])) + ((pB[4]+pB[5])+(pB[6]+pB[7]));

            // ---- P relayout (8 bpermutes each)
            const int A0 = (int)pk2(pA[0], pA[1]), A1 = (int)pk2(pA[2], pA[3]);
            const int A2 = (int)pk2(pA[4], pA[5]), A3 = (int)pk2(pA[6], pA[7]);
            const int B0w = (int)pk2(pB[0], pB[1]), B1w = (int)pk2(pB[2], pB[3]);
            const int B2w = (int)pk2(pB[4], pB[5]), B3w = (int)pk2(pB[6], pB[7]);
            int a0e = __builtin_amdgcn_ds_bpermute(addrE, A0);
            int a2e = __builtin_amdgcn_ds_bpermute(addrE, A2);
            int a1e = __builtin_amdgcn_ds_bpermute(addrE, A1);
            int a3e = __builtin_amdgcn_ds_bpermute(addrE, A3);
            int a0o = __builtin_amdgcn_ds_bpermute(addrO, A0);
            int a2o = __builtin_amdgcn_ds_bpermute(addrO, A2);
            int a1o = __builtin_amdgcn_ds_bpermute(addrO, A1);
            int a3o = __builtin_amdgcn_ds_bpermute(addrO, A3);
            int b0e = __builtin_amdgcn_ds_bpermute(addrE, B0w);
            int b2e = __builtin_amdgcn_ds_bpermute(addrE, B2w);
            int b1e = __builtin_amdgcn_ds_bpermute(addrE, B1w);
            int b3e = __builtin_amdgcn_ds_bpermute(addrE, B3w);
            int b0o = __builtin_amdgcn_ds_bpermute(addrO, B0w);
            int b2o = __builtin_amdgcn_ds_bpermute(addrO, B2w);
            int b1o = __builtin_amdgcn_ds_bpermute(addrO, B1w);
            int b3o = __builtin_amdgcn_ds_bpermute(addrO, B3w);
            u32x4 pwA, pwB;
            pwA[0] = (unsigned int)(useB ? a2e : a0e);
            pwA[1] = (unsigned int)(useB ? a3e : a1e);
            pwA[2] = (unsigned int)(useB ? a2o : a0o);
            pwA[3] = (unsigned int)(useB ? a3o : a1o);
            pwB[0] = (unsigned int)(useB ? b2e : b0e);
            pwB[1] = (unsigned int)(useB ? b3e : b1e);
            pwB[2] = (unsigned int)(useB ? b2o : b0o);
            pwB[3] = (unsigned int)(useB ? b3o : b1o);
            const short8 pbA = __builtin_bit_cast(short8, pwA);
            const short8 pbB = __builtin_bit_cast(short8, pwB);

            // ---- PV: each V fragment read feeds both accumulators
            #pragma unroll
            for (int n = 0; n < 8; ++n) {
                short8 vr = *(const short8*)&Kc[4096 + n * 512 + lane * 8];
                oA[n] = __builtin_amdgcn_mfma_f32_16x16x32_bf16(vr, pbA, oA[n], 0, 0, 0);
                oB[n] = __builtin_amdgcn_mfma_f32_16x16x32_bf16(vr, pbB, oB[n], 0, 0, 0);
            }

            asm volatile("s_waitcnt lgkmcnt(0)" ::: "memory");
            __builtin_amdgcn_s_barrier();
            __builtin_amdgcn_sched_barrier(0);
            cur = nb;
        }

        // ---- epilogue
        float ltA = lA;
        ltA += __shfl_xor(ltA, 16);
        ltA += __shfl_xor(ltA, 32);
        float ltB = lB;
        ltB += __shfl_xor(ltB, 16);
        ltB += __shfl_xor(ltB, 32);
        const bool valA = (qA < qlen), valB = (qB < qlen);
        const float invA = valA ? (1.0f / ltA) : 0.f;
        const float invB = valB ? (1.0f / ltB) : 0.f;
        float* opA = out + (((size_t)b * QQ + qA) * HH + h) * DD + g * 4;
        float* opB = out + (((size_t)b * QQ + qB) * HH + h) * DD + g * 4;
        #pragma unroll
        for (int n = 0; n < 8; ++n) {
            f32x4 wa, wb;
            wa[0] = oA[n][0] * invA; wa[1] = oA[n][1] * invA;
            wa[2] = oA[n][2] * invA; wa[3] = oA[n][3] * invA;
            wb[0] = oB[n][0] * invB; wb[1] = oB[n][1] * invB;
            wb[2] = oB[n][2] * invB; wb[3] = oB[n][3] * invB;
            *(f32x4*)&opA[n * 16] = wa;
            *(f32x4*)&opB[n * 16] = wb;
        }
    }
}

// ---------------- R1 fallback (proven) if ws too small ----------------
__global__ __launch_bounds__(256)
void segattn(const float* __restrict__ qs, const float* __restrict__ ks,
             const float* __restrict__ vs, const float* __restrict__ kc,
             const float* __restrict__ vc, const int* __restrict__ qlens,
             const int* __restrict__ clens, float* __restrict__ out)
{
    const int qt = blockIdx.x, h = blockIdx.y, b = blockIdx.z;
    const int tid = threadIdx.x, wave = tid >> 6, lane = tid & 63;
    const int g = lane >> 4, lc = lane & 15;
    const int qlen = qlens[b], clen = clens[b];
    const int q0 = qt * QT;
    if (q0 >= qlen) {
        f32x4 z = {0.f, 0.f, 0.f, 0.f};
        #pragma unroll
        for (int i2 = 0; i2 < 8; ++i2) {
            int f = tid + i2 * 256;
            int r = f >> 5, d4 = f & 31;
            *(f32x4*)&out[(((size_t)b * QQ + q0 + r) * HH + h) * DD + d4 * 4] = z;
        }
        return;
    }
    alignas(16) __shared__ unsigned short Kl[KT * DD];
    alignas(16) __shared__ unsigned short Vl[DD * 40];
    alignas(16) __shared__ unsigned short Pl[4][16][40];
    const float psc = 0.08838834764831845f * 1.4426950408889634f;
    const int qrow = q0 + wave * 16 + lc;
    const float* qp = qs + (((size_t)b * QQ + qrow) * HH + h) * DD;
    short8 qf[4];
    #pragma unroll
    for (int c = 0; c < 4; ++c) {
        f32x4 a0 = *(const f32x4*)&qp[c * 32 + g * 8];
        f32x4 a1 = *(const f32x4*)&qp[c * 32 + g * 8 + 4];
        short8 t;
        t[0] = (short)f2bf(a0[0] * psc); t[1] = (short)f2bf(a0[1] * psc);
        t[2] = (short)f2bf(a0[2] * psc); t[3] = (short)f2bf(a0[3] * psc);
        t[4] = (short)f2bf(a1[0] * psc); t[5] = (short)f2bf(a1[1] * psc);
        t[6] = (short)f2bf(a1[2] * psc); t[7] = (short)f2bf(a1[3] * psc);
        qf[c] = t;
    }
    f32x4 o[8];
    #pragma unroll
    for (int n = 0; n < 8; ++n) o[n] = (f32x4){0.f, 0.f, 0.f, 0.f};
    float m_[4] = {-3e38f, -3e38f, -3e38f, -3e38f};
    float l_[4] = {0.f, 0.f, 0.f, 0.f};
    int lim[4];
    #pragma unroll
    for (int qq = 0; qq < 4; ++qq) {
        int i = q0 + wave * 16 + g * 4 + qq;
        lim[qq] = (i < qlen) ? (clen + i + 1) : 0;
    }
    const int kmax = clen + min(q0 + QT, qlen);
    const int nt = (kmax + KT - 1) / KT;
    for (int t = 0; t < nt; ++t) {
        const int pbase = t * KT;
        __syncthreads();
        #pragma unroll
        for (int it = 0; it < 4; ++it) {
            int f = tid + it * 256;
            int key = f >> 5, d4 = f & 31;
            int p = pbase + key;
            const float *srck, *srcv;
            if (p < clen) {
                size_t off = (((size_t)b * SS + p) * HH + h) * DD + d4 * 4;
                srck = kc + off; srcv = vc + off;
            } else {
                int idx = p - clen; if (idx > QQ - 1) idx = QQ - 1;
                size_t off = (((size_t)b * QQ + idx) * HH + h) * DD + d4 * 4;
                srck = ks + off; srcv = vs + off;
            }
            f32x4 kv = *(const f32x4*)srck;
            f32x4 vv = *(const f32x4*)srcv;
            int ei = (key * DD + d4 * 4) ^ ((key & 7) << 3);
            typedef __attribute__((ext_vector_type(4))) unsigned short u16x4;
            u16x4 kb4 = {f2bf(kv[0]), f2bf(kv[1]), f2bf(kv[2]), f2bf(kv[3])};
            *(u16x4*)&Kl[ei] = kb4;
            int d0 = d4 * 4;
            Vl[(d0 + 0) * 40 + key] = f2bf(vv[0]);
            Vl[(d0 + 1) * 40 + key] = f2bf(vv[1]);
            Vl[(d0 + 2) * 40 + key] = f2bf(vv[2]);
            Vl[(d0 + 3) * 40 + key] = f2bf(vv[3]);
        }
        __syncthreads();
        f32x4 sc0 = {0.f, 0.f, 0.f, 0.f}, sc1 = {0.f, 0.f, 0.f, 0.f};
        #pragma unroll
        for (int c = 0; c < 4; ++c) {
            int i0 = (lc * DD + c * 32 + g * 8) ^ ((lc & 7) << 3);
            int i1 = ((16 + lc) * DD + c * 32 + g * 8) ^ (((16 + lc) & 7) << 3);
            short8 k0 = *(const short8*)&Kl[i0];
            short8 k1 = *(const short8*)&Kl[i1];
            sc0 = __builtin_amdgcn_mfma_f32_16x16x32_bf16(qf[c], k0, sc0, 0, 0, 0);
            sc1 = __builtin_amdgcn_mfma_f32_16x16x32_bf16(qf[c], k1, sc1, 0, 0, 0);
        }
        float pr0[4], pr1[4];
        #pragma unroll
        for (int qq = 0; qq < 4; ++qq) {
            float s0 = sc0[qq], s1 = sc1[qq];
            if (pbase + lc >= lim[qq])      s0 = -3e38f;
            if (pbase + 16 + lc >= lim[qq]) s1 = -3e38f;
            float pm = fmaxf(s0, s1);
            #pragma unroll
            for (int d2 = 1; d2 < 16; d2 <<= 1) pm = fmaxf(pm, __shfl_xor(pm, d2));
            float mn = fmaxf(m_[qq], pm);
            float alpha = exp2f(m_[qq] - mn);
            float p0 = exp2f(s0 - mn), p1 = exp2f(s1 - mn);
            float rs = p0 + p1;
            #pragma unroll
            for (int d2 = 1; d2 < 16; d2 <<= 1) rs += __shfl_xor(rs, d2);
            l_[qq] = l_[qq] * alpha + rs;
            m_[qq] = mn;
            pr0[qq] = p0; pr1[qq] = p1;
            #pragma unroll
            for (int n = 0; n < 8; ++n) o[n][qq] *= alpha;
        }
        #pragma unroll
        for (int qq = 0; qq < 4; ++qq) {
            Pl[wave][g * 4 + qq][lc]      = f2bf(pr0[qq]);
            Pl[wave][g * 4 + qq][16 + lc] = f2bf(pr1[qq]);
        }
        short8 pf = *(const short8*)&Pl[wave][lc][g * 8];
        #pragma unroll
        for (int n = 0; n < 8; ++n) {
            short8 vf = *(const short8*)&Vl[(n * 16 + lc) * 40 + g * 8];
            o[n] = __builtin_amdgcn_mfma_f32_16x16x32_bf16(pf, vf, o[n], 0, 0, 0);
        }
    }
    #pragma unroll
    for (int qq = 0; qq < 4; ++qq) {
        int i = q0 + wave * 16 + g * 4 + qq;
        bool val = (i < qlen);
        float inv = val ? (1.0f / l_[qq]) : 0.f;
        size_t ob = (((size_t)b * QQ + i) * HH + h) * DD + lc;
        #pragma unroll
        for (int n = 0; n < 8; ++n)
            out[ob + (size_t)n * 16] = val ? o[n][qq] * inv : 0.f;
    }
}

extern "C" void kernel_launch(void* const* d_in, const int* in_sizes, int n_in,
                              void* d_out, int out_size, void* d_ws, size_t ws_size,
                              hipStream_t stream) {
    const float* qs = (const float*)d_in[0];
    const float* ks = (const float*)d_in[1];
    const float* vs = (const float*)d_in[2];
    const float* kc = (const float*)d_in[3];
    const float* vc = (const float*)d_in[4];
    const int* ql = (const int*)d_in[5];
    const int* cl = (const int*)d_in[6];
    float* o = (float*)d_out;

    const size_t kv_elems = (size_t)BB * HH * NTILES * TILE_ELEMS;
    const size_t kv_bytes = kv_elems * 2 * sizeof(unsigned short);   // 128 MiB
    const size_t need = kv_bytes + 128;

    if (ws_size >= need) {
        unsigned short* Kws = (unsigned short*)d_ws;
        unsigned short* Vws = Kws + kv_elems;
        int* counter = (int*)((char*)d_ws + kv_bytes);
        hipMemsetAsync(counter, 0, 128, stream);                     // 8 subqueue counters
        dim3 pgrid(NTILES, HH, BB), pblk(256, 1, 1);
        hipLaunchKernelGGL(prep, pgrid, pblk, 0, stream, ks, vs, kc, vc, ql, cl, Kws, Vws);
        dim3 grid(1024, 1, 1), blk(256, 1, 1);
        hipLaunchKernelGGL(segattn_persist, grid, blk, 0, stream, qs, ql, cl, Kws, Vws, o, counter);
    } else {
        dim3 grid(QQ / QT, HH, BB), blk(256, 1, 1);
        hipLaunchKernelGGL(segattn, grid, blk, 0, stream, qs, ks, vs, kc, vc, ql, cl, o);
    }
}

// Round 11
// 169.593 us; speedup vs baseline: 1.8144x; 1.8144x over previous
//
#include <hip/hip_runtime.h>

// R11: R9's proven pipeline/queue/item-geometry, but per-wave math moved to
// mfma_f32_32x32x16 (32 q-rows/wave). Block = 2 waves = 64-row item ->
// LDS tile read by 2 waves not 4 => LDS bytes per unit work HALVED (R10's
// goal without its scheduling regression). Softmax row pair = (lane,lane+32):
// one shfl_xor(32); P relayout via cvt_pk_bf16 + shfl_xor(32) + selects.

#define BB 4
#define QQ 1024
#define SS 2048
#define HH 32
#define DD 128
#define QT 64
#define KT 32
#define NTILES 64
#define TILE_ELEMS 4096
#define NITEMS 2048

typedef __attribute__((ext_vector_type(8))) short short8;
typedef __attribute__((ext_vector_type(4))) float f32x4;
typedef __attribute__((ext_vector_type(16))) float f32x16;
typedef __attribute__((ext_vector_type(4))) unsigned int u32x4;
typedef __attribute__((ext_vector_type(8))) unsigned short u16x8;

__device__ __forceinline__ unsigned short f2bf(float f) {
    unsigned int u = __builtin_bit_cast(unsigned int, f);
    u += 0x7FFFu + ((u >> 16) & 1u);
    return (unsigned short)(u >> 16);
}
__device__ __forceinline__ unsigned int cvtpk(float lo, float hi) {
    unsigned int r;
    asm("v_cvt_pk_bf16_f32 %0, %1, %2" : "=v"(r) : "v"(lo), "v"(hi));
    return r;
}

// ---------------- prep: f32 cache/new -> bf16 32x32-fragment-ordered ws -------
// K tile (4096 hw): idx = c*512 + l*8 + e  ->  K[key=(l&31)][d = c*16 + (l>>5)*8 + e]
// V tile (4096 hw): idx = a*512 + l*8 + e, a=dchunk*2+kc
//                   ->  V[key = kc*16 + (l>>5)*8 + e][d = dchunk*32 + (l&31)]
__global__ __launch_bounds__(256)
void prep(const float* __restrict__ ks, const float* __restrict__ vs,
          const float* __restrict__ kc_, const float* __restrict__ vc,
          const int* __restrict__ qlens, const int* __restrict__ clens,
          unsigned short* __restrict__ Kws, unsigned short* __restrict__ Vws)
{
    const int tile = blockIdx.x, h = blockIdx.y, b = blockIdx.z;
    const int qlen = qlens[b], clen = clens[b];
    if (tile * KT >= clen + qlen) return;
    const int tid = threadIdx.x;
    unsigned short* kout = Kws + (((size_t)b * HH + h) * NTILES + tile) * TILE_ELEMS;
    unsigned short* vout = Vws + (((size_t)b * HH + h) * NTILES + tile) * TILE_ELEMS;

    #pragma unroll
    for (int h2 = 0; h2 < 2; ++h2) {
        const int idx8 = h2 * 2048 + tid * 8;
        const int c = idx8 >> 9, l = (idx8 >> 3) & 63;
        int key = tile * KT + (l & 31);
        const float* src;
        if (key < clen) {
            src = kc_ + (((size_t)b * SS + key) * HH + h) * DD;
        } else {
            int i2 = key - clen; if (i2 > QQ - 1) i2 = QQ - 1;
            src = ks + (((size_t)b * QQ + i2) * HH + h) * DD;
        }
        const int d0 = c * 16 + ((l >> 5) << 3);
        f32x4 a0 = *(const f32x4*)&src[d0];
        f32x4 a1 = *(const f32x4*)&src[d0 + 4];
        u16x8 w;
        w[0] = f2bf(a0[0]); w[1] = f2bf(a0[1]); w[2] = f2bf(a0[2]); w[3] = f2bf(a0[3]);
        w[4] = f2bf(a1[0]); w[5] = f2bf(a1[1]); w[6] = f2bf(a1[2]); w[7] = f2bf(a1[3]);
        *(u16x8*)&kout[idx8] = w;
    }
    #pragma unroll
    for (int h2 = 0; h2 < 2; ++h2) {
        const int idx8 = h2 * 2048 + tid * 8;
        const int a = idx8 >> 9, l = (idx8 >> 3) & 63;
        const int dchunk = a >> 1, kcc = a & 1;
        const int d = dchunk * 32 + (l & 31);
        const int kb = tile * KT + kcc * 16 + ((l >> 5) << 3);
        u16x8 w;
        #pragma unroll
        for (int e = 0; e < 8; ++e) {
            int key = kb + e;
            const float* src;
            if (key < clen) {
                src = vc + (((size_t)b * SS + key) * HH + h) * DD;
            } else {
                int i2 = key - clen; if (i2 > QQ - 1) i2 = QQ - 1;
                src = vs + (((size_t)b * QQ + i2) * HH + h) * DD;
            }
            w[e] = f2bf(src[d]);
        }
        *(u16x8*)&vout[idx8] = w;
    }
}

// ---------------- hot: 128-thr blocks, 2 waves x 32 rows, 32x32 MFMA ---------
__global__ __launch_bounds__(128, 2)
void segattn_persist(const float* __restrict__ qs, const int* __restrict__ qlens,
                     const int* __restrict__ clens,
                     const unsigned short* __restrict__ Kws,
                     const unsigned short* __restrict__ Vws,
                     float* __restrict__ out, int* __restrict__ counter)
{
    __shared__ int s_item;
    alignas(16) __shared__ unsigned short KVl[2][8192];  // K [0,4096) V [4096,8192)

    const int tid = threadIdx.x, w = tid >> 6, lane = tid & 63;
    const int q31 = lane & 31, hi = lane >> 5;
    const bool hiL = (hi != 0);
    const float psc = 0.08838834764831845f * 1.4426950408889634f;
    const int sbase = w * 2048 + lane * 8;   // this wave's staging slice base (hw)

    for (;;) {
        if (tid == 0) s_item = atomicAdd(counter, 1);
        __syncthreads();
        const int idx = s_item;
        __syncthreads();
        if (idx >= NITEMS) break;

        const int qt = 15 - (idx >> 7);      // heavy-first pop order (LPT)
        const int b = idx & 3, h = (idx >> 2) & 31;
        const int qlen = qlens[b], clen = clens[b];
        const int q0 = qt * QT;

        if (q0 >= qlen) {                    // fully padded tile -> zeros
            f32x4 z = {0.f, 0.f, 0.f, 0.f};
            #pragma unroll
            for (int i2 = 0; i2 < 16; ++i2) {
                int f = tid + i2 * 128;
                int r = f >> 5, d4 = f & 31;
                *(f32x4*)&out[(((size_t)b * QQ + q0 + r) * HH + h) * DD + d4 * 4] = z;
            }
            continue;
        }

        const int q = q0 + w * 32 + q31;
        const float* qp = qs + (((size_t)b * QQ + q) * HH + h) * DD;
        short8 qf[8];
        #pragma unroll
        for (int c = 0; c < 8; ++c) {
            const int d0 = c * 16 + hi * 8;
            f32x4 a0 = *(const f32x4*)&qp[d0];
            f32x4 a1 = *(const f32x4*)&qp[d0 + 4];
            short8 t;
            t[0] = (short)f2bf(a0[0] * psc); t[1] = (short)f2bf(a0[1] * psc);
            t[2] = (short)f2bf(a0[2] * psc); t[3] = (short)f2bf(a0[3] * psc);
            t[4] = (short)f2bf(a1[0] * psc); t[5] = (short)f2bf(a1[1] * psc);
            t[6] = (short)f2bf(a1[2] * psc); t[7] = (short)f2bf(a1[3] * psc);
            qf[c] = t;
        }

        const int lim_l = (q < qlen) ? (clen + q + 1) : 0;
        const int wq0 = q0 + w * 32;
        const int lim_min = (wq0 + 31 < qlen) ? (clen + wq0 + 1) : 0;

        float m_ = -3e38f, l_ = 0.f;         // l_ lane-partial (pair-reduced at end)
        f32x16 o0 = {0}, o1 = {0}, o2 = {0}, o3 = {0};

        const int kmax = clen + min(q0 + QT, qlen);
        const int nt = (kmax + KT - 1) / KT;
        const unsigned short* Kb = Kws + ((size_t)(b * HH + h)) * NTILES * TILE_ELEMS;
        const unsigned short* Vb = Vws + ((size_t)(b * HH + h)) * NTILES * TILE_ELEMS;

        // ---- prologue: tile 0 -> buf0
        {
            #pragma unroll
            for (int j = 0; j < 4; ++j) {
                u32x4 ak = *(const u32x4*)&Kb[sbase + j * 512];
                u32x4 av = *(const u32x4*)&Vb[sbase + j * 512];
                *(u32x4*)&KVl[0][sbase + j * 512]        = ak;
                *(u32x4*)&KVl[0][4096 + sbase + j * 512] = av;
            }
            asm volatile("s_waitcnt lgkmcnt(0)" ::: "memory");
            __builtin_amdgcn_s_barrier();
            __builtin_amdgcn_sched_barrier(0);
        }
        // reg-stage tile 1
        const int t1 = (nt > 1) ? 1 : 0;
        const unsigned short* kt1 = Kb + (size_t)t1 * TILE_ELEMS;
        const unsigned short* vt1 = Vb + (size_t)t1 * TILE_ELEMS;
        u32x4 sk0 = *(const u32x4*)&kt1[sbase];
        u32x4 sk1 = *(const u32x4*)&kt1[sbase + 512];
        u32x4 sk2 = *(const u32x4*)&kt1[sbase + 1024];
        u32x4 sk3 = *(const u32x4*)&kt1[sbase + 1536];
        u32x4 sv0 = *(const u32x4*)&vt1[sbase];
        u32x4 sv1 = *(const u32x4*)&vt1[sbase + 512];
        u32x4 sv2 = *(const u32x4*)&vt1[sbase + 1024];
        u32x4 sv3 = *(const u32x4*)&vt1[sbase + 1536];

        int cur = 0;
        for (int t = 0; t < nt; ++t) {
            const int nb = cur ^ 1;
            *(u32x4*)&KVl[nb][sbase]               = sk0;
            *(u32x4*)&KVl[nb][sbase + 512]         = sk1;
            *(u32x4*)&KVl[nb][sbase + 1024]        = sk2;
            *(u32x4*)&KVl[nb][sbase + 1536]        = sk3;
            *(u32x4*)&KVl[nb][4096 + sbase]        = sv0;
            *(u32x4*)&KVl[nb][4096 + sbase + 512]  = sv1;
            *(u32x4*)&KVl[nb][4096 + sbase + 1024] = sv2;
            *(u32x4*)&KVl[nb][4096 + sbase + 1536] = sv3;
            const int t2c = (t + 2 < nt) ? t + 2 : (nt - 1);
            const unsigned short* kt2 = Kb + (size_t)t2c * TILE_ELEMS;
            const unsigned short* vt2 = Vb + (size_t)t2c * TILE_ELEMS;
            sk0 = *(const u32x4*)&kt2[sbase];
            sk1 = *(const u32x4*)&kt2[sbase + 512];
            sk2 = *(const u32x4*)&kt2[sbase + 1024];
            sk3 = *(const u32x4*)&kt2[sbase + 1536];
            sv0 = *(const u32x4*)&vt2[sbase];
            sv1 = *(const u32x4*)&vt2[sbase + 512];
            sv2 = *(const u32x4*)&vt2[sbase + 1024];
            sv3 = *(const u32x4*)&vt2[sbase + 1536];
            asm volatile("s_waitcnt lgkmcnt(0)" ::: "memory");
            __builtin_amdgcn_s_barrier();
            __builtin_amdgcn_sched_barrier(0);

            // ---- compute tile t
            const unsigned short* Kc = &KVl[cur][0];
            const int pbase = t * KT;
            f32x16 s = {0};
            #pragma unroll
            for (int c = 0; c < 8; ++c) {
                short8 kf = *(const short8*)&Kc[c * 512 + lane * 8];
                s = __builtin_amdgcn_mfma_f32_32x32x16_bf16(kf, qf[c], s, 0, 0, 0);
            }
            if (pbase + KT > lim_min) {
                #pragma unroll
                for (int r = 0; r < 16; ++r) {
                    const int kk = pbase + (r & 3) + ((r >> 2) << 3) + hi * 4;
                    if (kk >= lim_l) s[r] = -3e38f;
                }
            }
            // row max over this lane's 16 k's
            float pm = fmaxf(fmaxf(fmaxf(fmaxf(s[0], s[1]), fmaxf(s[2], s[3])),
                                   fmaxf(fmaxf(s[4], s[5]), fmaxf(s[6], s[7]))),
                             fmaxf(fmaxf(fmaxf(s[8], s[9]), fmaxf(s[10], s[11])),
                                   fmaxf(fmaxf(s[12], s[13]), fmaxf(s[14], s[15]))));
            if (__any(pm > m_ + 8.0f)) {
                pm = fmaxf(pm, __shfl_xor(pm, 32));
                const float mn = fmaxf(m_, pm);
                const float alpha = __builtin_amdgcn_exp2f(m_ - mn);
                m_ = mn;
                l_ *= alpha;
                #pragma unroll
                for (int r = 0; r < 16; ++r) {
                    o0[r] *= alpha; o1[r] *= alpha; o2[r] *= alpha; o3[r] *= alpha;
                }
            }
            float p[16];
            #pragma unroll
            for (int r = 0; r < 16; ++r) p[r] = __builtin_amdgcn_exp2f(s[r] - m_);
            l_ += (((p[0]+p[1])+(p[2]+p[3])) + ((p[4]+p[5])+(p[6]+p[7])))
                + (((p[8]+p[9])+(p[10]+p[11])) + ((p[12]+p[13])+(p[14]+p[15])));

            // pack to bf16 words; exchange row halves via shfl_xor(32)
            const unsigned int w0 = cvtpk(p[0],  p[1]);
            const unsigned int w1 = cvtpk(p[2],  p[3]);
            const unsigned int w2 = cvtpk(p[4],  p[5]);
            const unsigned int w3 = cvtpk(p[6],  p[7]);
            const unsigned int w4 = cvtpk(p[8],  p[9]);
            const unsigned int w5 = cvtpk(p[10], p[11]);
            const unsigned int w6 = cvtpk(p[12], p[13]);
            const unsigned int w7 = cvtpk(p[14], p[15]);
            const unsigned int x0 = (unsigned int)__shfl_xor((int)w0, 32);
            const unsigned int x1 = (unsigned int)__shfl_xor((int)w1, 32);
            const unsigned int x2 = (unsigned int)__shfl_xor((int)w2, 32);
            const unsigned int x3 = (unsigned int)__shfl_xor((int)w3, 32);
            const unsigned int x4 = (unsigned int)__shfl_xor((int)w4, 32);
            const unsigned int x5 = (unsigned int)__shfl_xor((int)w5, 32);
            const unsigned int x6 = (unsigned int)__shfl_xor((int)w6, 32);
            const unsigned int x7 = (unsigned int)__shfl_xor((int)w7, 32);
            u32x4 pb0w, pb1w;
            pb0w[0] = hiL ? x2 : w0;  pb0w[1] = hiL ? x3 : w1;
            pb0w[2] = hiL ? w2 : x0;  pb0w[3] = hiL ? w3 : x1;
            pb1w[0] = hiL ? x6 : w4;  pb1w[1] = hiL ? x7 : w5;
            pb1w[2] = hiL ? w6 : x4;  pb1w[3] = hiL ? w7 : x5;
            const short8 pb0 = __builtin_bit_cast(short8, pb0w);
            const short8 pb1 = __builtin_bit_cast(short8, pb1w);

            // PV: O[dchunk] += V^T[dchunk][k] * P
            {
                short8 va = *(const short8*)&Kc[4096 + 0 * 512 + lane * 8];
                short8 vb = *(const short8*)&Kc[4096 + 1 * 512 + lane * 8];
                o0 = __builtin_amdgcn_mfma_f32_32x32x16_bf16(va, pb0, o0, 0, 0, 0);
                o0 = __builtin_amdgcn_mfma_f32_32x32x16_bf16(vb, pb1, o0, 0, 0, 0);
            }
            {
                short8 va = *(const short8*)&Kc[4096 + 2 * 512 + lane * 8];
                short8 vb = *(const short8*)&Kc[4096 + 3 * 512 + lane * 8];
                o1 = __builtin_amdgcn_mfma_f32_32x32x16_bf16(va, pb0, o1, 0, 0, 0);
                o1 = __builtin_amdgcn_mfma_f32_32x32x16_bf16(vb, pb1, o1, 0, 0, 0);
            }
            {
                short8 va = *(const short8*)&Kc[4096 + 4 * 512 + lane * 8];
                short8 vb = *(const short8*)&Kc[4096 + 5 * 512 + lane * 8];
                o2 = __builtin_amdgcn_mfma_f32_32x32x16_bf16(va, pb0, o2, 0, 0, 0);
                o2 = __builtin_amdgcn_mfma_f32_32x32x16_bf16(vb, pb1, o2, 0, 0, 0);
            }
            {
                short8 va = *(const short8*)&Kc[4096 + 6 * 512 + lane * 8];
                short8 vb = *(const short8*)&Kc[4096 + 7 * 512 + lane * 8];
                o3 = __builtin_amdgcn_mfma_f32_32x32x16_bf16(va, pb0, o3, 0, 0, 0);
                o3 = __builtin_amdgcn_mfma_f32_32x32x16_bf16(vb, pb1, o3, 0, 0, 0);
            }

            asm volatile("s_waitcnt lgkmcnt(0)" ::: "memory");
            __builtin_amdgcn_s_barrier();
            __builtin_amdgcn_sched_barrier(0);
            cur = nb;
        }

        // ---- epilogue: pair-reduce l, store O (rows of 4 consecutive d)
        float lt = l_ + __shfl_xor(l_, 32);
        const bool val = (q < qlen);
        const float inv = val ? (1.0f / lt) : 0.f;
        float* op = out + (((size_t)b * QQ + q) * HH + h) * DD;
        #pragma unroll
        for (int rr = 0; rr < 4; ++rr) {
            f32x4 wv;
            const int d0 = rr * 8 + hi * 4;
            wv[0] = o0[rr*4+0]*inv; wv[1] = o0[rr*4+1]*inv;
            wv[2] = o0[rr*4+2]*inv; wv[3] = o0[rr*4+3]*inv;
            *(f32x4*)&op[d0] = wv;
            wv[0] = o1[rr*4+0]*inv; wv[1] = o1[rr*4+1]*inv;
            wv[2] = o1[rr*4+2]*inv; wv[3] = o1[rr*4+3]*inv;
            *(f32x4*)&op[32 + d0] = wv;
            wv[0] = o2[rr*4+0]*inv; wv[1] = o2[rr*4+1]*inv;
            wv[2] = o2[rr*4+2]*inv; wv[3] = o2[rr*4+3]*inv;
            *(f32x4*)&op[64 + d0] = wv;
            wv[0] = o3[rr*4+0]*inv; wv[1] = o3[rr*4+1]*inv;
            wv[2] = o3[rr*4+2]*inv; wv[3] = o3[rr*4+3]*inv;
            *(f32x4*)&op[96 + d0] = wv;
        }
    }
}

// ---------------- R1 fallback (proven) if ws too small ----------------
__global__ __launch_bounds__(256)
void segattn(const float* __restrict__ qs, const float* __restrict__ ks,
             const float* __restrict__ vs, const float* __restrict__ kc,
             const float* __restrict__ vc, const int* __restrict__ qlens,
             const int* __restrict__ clens, float* __restrict__ out)
{
    const int qt = blockIdx.x, h = blockIdx.y, b = blockIdx.z;
    const int tid = threadIdx.x, wave = tid >> 6, lane = tid & 63;
    const int g = lane >> 4, lc = lane & 15;
    const int qlen = qlens[b], clen = clens[b];
    const int q0 = qt * QT;
    if (q0 >= qlen) {
        f32x4 z = {0.f, 0.f, 0.f, 0.f};
        #pragma unroll
        for (int i2 = 0; i2 < 8; ++i2) {
            int f = tid + i2 * 256;
            int r = f >> 5, d4 = f & 31;
            *(f32x4*)&out[(((size_t)b * QQ + q0 + r) * HH + h) * DD + d4 * 4] = z;
        }
        return;
    }
    alignas(16) __shared__ unsigned short Kl[KT * DD];
    alignas(16) __shared__ unsigned short Vl[DD * 40];
    alignas(16) __shared__ unsigned short Pl[4][16][40];
    const float psc = 0.08838834764831845f * 1.4426950408889634f;
    const int qrow = q0 + wave * 16 + lc;
    const float* qp = qs + (((size_t)b * QQ + qrow) * HH + h) * DD;
    short8 qf[4];
    #pragma unroll
    for (int c = 0; c < 4; ++c) {
        f32x4 a0 = *(const f32x4*)&qp[c * 32 + g * 8];
        f32x4 a1 = *(const f32x4*)&qp[c * 32 + g * 8 + 4];
        short8 t;
        t[0] = (short)f2bf(a0[0] * psc); t[1] = (short)f2bf(a0[1] * psc);
        t[2] = (short)f2bf(a0[2] * psc); t[3] = (short)f2bf(a0[3] * psc);
        t[4] = (short)f2bf(a1[0] * psc); t[5] = (short)f2bf(a1[1] * psc);
        t[6] = (short)f2bf(a1[2] * psc); t[7] = (short)f2bf(a1[3] * psc);
        qf[c] = t;
    }
    f32x4 o[8];
    #pragma unroll
    for (int n = 0; n < 8; ++n) o[n] = (f32x4){0.f, 0.f, 0.f, 0.f};
    float m_[4] = {-3e38f, -3e38f, -3e38f, -3e38f};
    float l_[4] = {0.f, 0.f, 0.f, 0.f};
    int lim[4];
    #pragma unroll
    for (int qq = 0; qq < 4; ++qq) {
        int i = q0 + wave * 16 + g * 4 + qq;
        lim[qq] = (i < qlen) ? (clen + i + 1) : 0;
    }
    const int kmax = clen + min(q0 + QT, qlen);
    const int nt = (kmax + KT - 1) / KT;
    for (int t = 0; t < nt; ++t) {
        const int pbase = t * KT;
        __syncthreads();
        #pragma unroll
        for (int it = 0; it < 4; ++it) {
            int f = tid + it * 256;
            int key = f >> 5, d4 = f & 31;
            int p = pbase + key;
            const float *srck, *srcv;
            if (p < clen) {
                size_t off = (((size_t)b * SS + p) * HH + h) * DD + d4 * 4;
                srck = kc + off; srcv = vc + off;
            } else {
                int idx = p - clen; if (idx > QQ - 1) idx = QQ - 1;
                size_t off = (((size_t)b * QQ + idx) * HH + h) * DD + d4 * 4;
                srck = ks + off; srcv = vs + off;
            }
            f32x4 kv = *(const f32x4*)srck;
            f32x4 vv = *(const f32x4*)srcv;
            int ei = (key * DD + d4 * 4) ^ ((key & 7) << 3);
            typedef __attribute__((ext_vector_type(4))) unsigned short u16x4;
            u16x4 kb4 = {f2bf(kv[0]), f2bf(kv[1]), f2bf(kv[2]), f2bf(kv[3])};
            *(u16x4*)&Kl[ei] = kb4;
            int d0 = d4 * 4;
            Vl[(d0 + 0) * 40 + key] = f2bf(vv[0]);
            Vl[(d0 + 1) * 40 + key] = f2bf(vv[1]);
            Vl[(d0 + 2) * 40 + key] = f2bf(vv[2]);
            Vl[(d0 + 3) * 40 + key] = f2bf(vv[3]);
        }
        __syncthreads();
        f32x4 sc0 = {0.f, 0.f, 0.f, 0.f}, sc1 = {0.f, 0.f, 0.f, 0.f};
        #pragma unroll
        for (int c = 0; c < 4; ++c) {
            int i0 = (lc * DD + c * 32 + g * 8) ^ ((lc & 7) << 3);
            int i1 = ((16 + lc) * DD + c * 32 + g * 8) ^ (((16 + lc) & 7) << 3);
            short8 k0 = *(const short8*)&Kl[i0];
            short8 k1 = *(const short8*)&Kl[i1];
            sc0 = __builtin_amdgcn_mfma_f32_16x16x32_bf16(qf[c], k0, sc0, 0, 0, 0);
            sc1 = __builtin_amdgcn_mfma_f32_16x16x32_bf16(qf[c], k1, sc1, 0, 0, 0);
        }
        float pr0[4], pr1[4];
        #pragma unroll
        for (int qq = 0; qq < 4; ++qq) {
            float s0 = sc0[qq], s1 = sc1[qq];
            if (pbase + lc >= lim[qq])      s0 = -3e38f;
            if (pbase + 16 + lc >= lim[qq]) s1 = -3e38f;
            float pm = fmaxf(s0, s1);
            #pragma unroll
            for (int d2 = 1; d2 < 16; d2 <<= 1) pm = fmaxf(pm, __shfl_xor(pm, d2));
            float mn = fmaxf(m_[qq], pm);
            float alpha = exp2f(m_[qq] - mn);
            float p0 = exp2f(s0 - mn), p1 = exp2f(s1 - mn);
            float rs = p0 + p1;
            #pragma unroll
            for (int d2 = 1; d2 < 16; d2 <<= 1) rs += __shfl_xor(rs, d2);
            l_[qq] = l_[qq] * alpha + rs;
            m_[qq] = mn;
            pr0[qq] = p0; pr1[qq] = p1;
            #pragma unroll
            for (int n = 0; n < 8; ++n) o[n][qq] *= alpha;
        }
        #pragma unroll
        for (int qq = 0; qq < 4; ++qq) {
            Pl[wave][g * 4 + qq][lc]      = f2bf(pr0[qq]);
            Pl[wave][g * 4 + qq][16 + lc] = f2bf(pr1[qq]);
        }
        short8 pf = *(const short8*)&Pl[wave][lc][g * 8];
        #pragma unroll
        for (int n = 0; n < 8; ++n) {
            short8 vf = *(const short8*)&Vl[(n * 16 + lc) * 40 + g * 8];
            o[n] = __builtin_amdgcn_mfma_f32_16x16x32_bf16(pf, vf, o[n], 0, 0, 0);
        }
    }
    #pragma unroll
    for (int qq = 0; qq < 4; ++qq) {
        int i = q0 + wave * 16 + g * 4 + qq;
        bool val = (i < qlen);
        float inv = val ? (1.0f / l_[qq]) : 0.f;
        size_t ob = (((size_t)b * QQ + i) * HH + h) * DD + lc;
        #pragma unroll
        for (int n = 0; n < 8; ++n)
            out[ob + (size_t)n * 16] = val ? o[n][qq] * inv : 0.f;
    }
}

extern "C" void kernel_launch(void* const* d_in, const int* in_sizes, int n_in,
                              void* d_out, int out_size, void* d_ws, size_t ws_size,
                              hipStream_t stream) {
    const float* qs = (const float*)d_in[0];
    const float* ks = (const float*)d_in[1];
    const float* vs = (const float*)d_in[2];
    const float* kc = (const float*)d_in[3];
    const float* vc = (const float*)d_in[4];
    const int* ql = (const int*)d_in[5];
    const int* cl = (const int*)d_in[6];
    float* o = (float*)d_out;

    const size_t kv_elems = (size_t)BB * HH * NTILES * TILE_ELEMS;
    const size_t kv_bytes = kv_elems * 2 * sizeof(unsigned short);   // 128 MiB
    const size_t need = kv_bytes + 128;

    if (ws_size >= need) {
        unsigned short* Kws = (unsigned short*)d_ws;
        unsigned short* Vws = Kws + kv_elems;
        int* counter = (int*)((char*)d_ws + kv_bytes);
        hipMemsetAsync(counter, 0, sizeof(int), stream);
        dim3 pgrid(NTILES, HH, BB), pblk(256, 1, 1);
        hipLaunchKernelGGL(prep, pgrid, pblk, 0, stream, ks, vs, kc, vc, ql, cl, Kws, Vws);
        dim3 grid(1024, 1, 1), blk(128, 1, 1);
        hipLaunchKernelGGL(segattn_persist, grid, blk, 0, stream, qs, ql, cl, Kws, Vws, o, counter);
    } else {
        dim3 grid(QQ / QT, HH, BB), blk(256, 1, 1);
        hipLaunchKernelGGL(segattn, grid, blk, 0, stream, qs, ks, vs, kc, vc, ql, cl, o);
    }
}